// Round 14
// baseline (220.988 us; speedup 1.0000x reference)
//
#include <hip/hip_runtime.h>
#include <stdint.h>

// Causal attention, B=4, SQ=SK=2048, D=1024, fp32 in/out, bf16 MFMA compute.
// R14 = R13 engine restructured to 16 waves/block (1024 thr) with <=128 total
//      regs/wave (o_acc halved to 32 AGPR via 64-wide D slices; QK split by
//      q-subtile) so all 16 waves are resident on one CU (R13's 8-wave shape
//      needed ~192 regs/wave -> could never pack 2 blocks). Same kv-split +
//      combine + swapped-QK^T + register softmax + panel layouts.
// Layouts: Kp[b][kv/16][d/8][kv%16][8d]  (A-frag load = 1KB/wave contiguous)
//          Vp[b][sk/32][d][sk%32]        (PV frag load = 1KB/wave contiguous)

#define B_SZ 4
#define SEQ 2048
#define DIM 1024
#define QBLK 32
#define KVBLK 128
#define NWAVES 16
#define PAN  ((size_t)DIM * 32)   // elems per 32-kv V panel
#define KPAN ((size_t)DIM * 16)   // elems per 16-kv K panel

typedef __bf16 bf16x8 __attribute__((ext_vector_type(8)));
typedef unsigned short u16x8 __attribute__((ext_vector_type(8)));
typedef unsigned short u16x4 __attribute__((ext_vector_type(4)));
typedef float f32x4 __attribute__((ext_vector_type(4)));

__device__ __forceinline__ unsigned short f2bf(float f) {
  union { float f; uint32_t u; } c; c.f = f;
  uint32_t u = c.u;
  u += 0x7FFFu + ((u >> 16) & 1u);   // RNE
  return (unsigned short)(u >> 16);
}

// K[b][kv][d] fp32 -> Kp[b][kv/16][d/8][kv%16][8] bf16
__global__ void transpose_k_kernel(const float* __restrict__ in,
                                   unsigned short* __restrict__ out) {
  const int b   = blockIdx.z;
  const int kv0 = blockIdx.y * 16;
  const int d0  = blockIdx.x * 128;
  const int t   = threadIdx.x;          // 256
  const int kvl = t >> 4;               // 0..15
  const int uu  = t & 15;               // 0..15 d-units
  const int d   = d0 + uu * 8;
  const float* src = in + (size_t)b * SEQ * DIM + (size_t)(kv0 + kvl) * DIM + d;
  f32x4 a = *(const f32x4*)(src);
  f32x4 c = *(const f32x4*)(src + 4);
  u16x8 pk;
#pragma unroll
  for (int j = 0; j < 4; ++j) { pk[j] = f2bf(a[j]); pk[4 + j] = f2bf(c[j]); }
  *(u16x8*)(out + (size_t)b * SEQ * DIM + (size_t)blockIdx.y * KPAN
            + (size_t)(d >> 3) * 128 + kvl * 8) = pk;
}

// V[b][sk][d] fp32 -> Vp[b][sk/32][d][sk%32] bf16 (panel-transposed)
__global__ void transpose_v_kernel(const float* __restrict__ in,
                                   unsigned short* __restrict__ out) {
  __shared__ unsigned short tile[32][33];
  const int b  = blockIdx.z;
  const int s0 = blockIdx.y * 32;
  const int d0 = blockIdx.x * 32;
  const int t  = threadIdx.x;
  const int r  = t >> 3;
  const int c4 = (t & 7) * 4;
  const size_t ibase = (size_t)b * SEQ * DIM;
  const size_t obase = (size_t)b * DIM * SEQ;

  f32x4 v = *(const f32x4*)(in + ibase + (size_t)(s0 + r) * DIM + d0 + c4);
#pragma unroll
  for (int j = 0; j < 4; ++j) tile[r][c4 + j] = f2bf(v[j]);
  __syncthreads();
  u16x4 o;
#pragma unroll
  for (int j = 0; j < 4; ++j) o[j] = tile[c4 + j][r];
  *(u16x4*)(out + obase + (size_t)(s0 >> 5) * PAN + (size_t)(d0 + r) * 32 + c4) = o;
}

__device__ __forceinline__ int imin(int a, int b) { return a < b ? a : b; }

__global__ __launch_bounds__(1024, 4) void attn_part(
    const float* __restrict__ Qf, const unsigned short* __restrict__ Kp,
    const unsigned short* __restrict__ Vp, float* __restrict__ Out,
    float* __restrict__ Opart, float* __restrict__ Ml, int mode) {
  const int tid  = threadIdx.x;
  const int lane = tid & 63;
  const int wv   = tid >> 6;        // 0..15
  const int s8   = wv & 7;          // QK kv strip
  const int h    = wv >> 3;         // QK q-subtile (nt) owned for softmax
  const int g    = lane >> 4;       // 0..3
  const int i16  = lane & 15;
  const int swz  = i16 & 7;

  // ---- work-item decode: chunk-major, XCD-affine, heavy-first ----
  const int IPX = (mode == 2) ? 80 : (mode == 1) ? 48 : 32;
  const int IPB = (mode == 2) ? 160 : (mode == 1) ? 96 : 64;
  const int item  = (blockIdx.x & 7) * IPX + (blockIdx.x >> 3);
  const int batch = item / IPB;
  const int r     = IPB - 1 - (item % IPB);

  int qt, kvlo, kvhi, slot;
  if (mode == 2) {
    if (r < 16)       { qt = r;             kvlo = 0;    kvhi = 32 * qt + 32;             slot = -1; }
    else if (r < 64)  { qt = r;             kvlo = 0;    kvhi = 512;                      slot = batch * 144 + (r - 16); }
    else if (r < 112) { qt = 16 + (r - 64); kvlo = 512;  kvhi = imin(1024, 32 * qt + 32); slot = batch * 144 + (r - 16); }
    else if (r < 144) { qt = 32 + (r - 112); kvlo = 1024; kvhi = imin(1536, 32 * qt + 32); slot = batch * 144 + (r - 16); }
    else              { qt = 48 + (r - 144); kvlo = 1536; kvhi = 32 * qt + 32;            slot = batch * 144 + (r - 16); }
  } else if (mode == 1) {
    if (r < 32)       { qt = r;             kvlo = 0;    kvhi = 32 * qt + 32;  slot = -1; }
    else if (r < 64)  { qt = 32 + (r - 32); kvlo = 0;    kvhi = 1024;          slot = batch * 64 + (r - 32); }
    else              { qt = 32 + (r - 64); kvlo = 1024; kvhi = 32 * qt + 32;  slot = batch * 64 + (r - 32); }
  } else {
    qt = r; kvlo = 0; kvhi = 32 * qt + 32; slot = -1;
  }

  const int q0 = qt * QBLK;
  const size_t boff = (size_t)batch * SEQ * DIM;

  __shared__ __align__(16) unsigned short Qs[QBLK * 1024];   // 64 KB swizzled
  __shared__ __align__(16) unsigned short Pl[QBLK * KVBLK];  // 8 KB swizzled
  __shared__ float pmaxT[QBLK][12];
  __shared__ float psumT[QBLK][12];

  // ---- stage Q: fp32 -> bf16 LDS, 16B-slot XOR swizzle (slot ^ (row&7)) ----
  {
    const int row = tid >> 5;          // 0..31
    const int s0  = tid & 31;
    const float* qrow = Qf + boff + (size_t)(q0 + row) * DIM;
#pragma unroll
    for (int k = 0; k < 4; ++k) {
      const int slot2 = s0 + 32 * k;   // 128 slots of 8 bf16
      f32x4 a = *(const f32x4*)(qrow + slot2 * 8);
      f32x4 b = *(const f32x4*)(qrow + slot2 * 8 + 4);
      u16x8 pk;
#pragma unroll
      for (int j = 0; j < 4; ++j) { pk[j] = f2bf(a[j]); pk[4 + j] = f2bf(b[j]); }
      *(u16x8*)(Qs + row * 1024 + (slot2 ^ (row & 7)) * 8) = pk;
    }
  }

  const f32x4 zero4 = {0.f, 0.f, 0.f, 0.f};
  f32x4 o_acc[4][2];                  // [mt d-16][nt q-16]; D slice 64/wave
#pragma unroll
  for (int mt = 0; mt < 4; ++mt)
#pragma unroll
    for (int nt = 0; nt < 2; ++nt) o_acc[mt][nt] = zero4;

  float m_reg[2] = {-1e30f, -1e30f};
  float l_reg[2] = {0.f, 0.f};

  const int ntiles = (kvhi - kvlo + KVBLK - 1) >> 7;
  // per-lane K base: strip s8 -> panel (kv0>>4)+s8, unit row i16
  const unsigned short* kb = Kp + boff + (size_t)s8 * KPAN + i16 * 8;
  // per-lane V base: d-row (wv*64 + i16), kv g*8
  const unsigned short* vb = Vp + boff + (size_t)(wv * 64 + i16) * 32 + g * 8;

  __syncthreads();   // Q visible

  for (int t = 0; t < ntiles; ++t) {
    const int kv0 = kvlo + t * KVBLK;
    const unsigned short* kt = kb + (size_t)(kv0 >> 4) * KPAN;  // strip panel
    const size_t vt0 = (size_t)(kv0 >> 5) * PAN;                // V panel base

    f32x4 sacc = zero4;
    bf16x8 vA[4], vB[4];   // V ring: 2 x 4 mt

    // ---- QK^T: 8 phases, K frags direct global->reg (coalesced) ----
#pragma unroll
    for (int c = 0; c < 8; ++c) {
      if (c == 0) {   // issue V frags kc0 (vA), kc1 (vB) early
#pragma unroll
        for (int mt = 0; mt < 4; ++mt) {
          vA[mt] = __builtin_bit_cast(bf16x8,
              *(const u16x8*)(vb + vt0 + (size_t)mt * 512));
          vB[mt] = __builtin_bit_cast(bf16x8,
              *(const u16x8*)(vb + vt0 + PAN + (size_t)mt * 512));
        }
      }
      const unsigned short* qrb = Qs + (h * 16 + i16) * 1024;
      bf16x8 kf[4], qf[4];
#pragma unroll
      for (int kk = 0; kk < 4; ++kk) {
        kf[kk] = __builtin_bit_cast(bf16x8,
            *(const u16x8*)(kt + (size_t)(c * 16 + kk * 4 + g) * 128));
        qf[kk] = __builtin_bit_cast(bf16x8,
            *(const u16x8*)(qrb + ((c * 16 + kk * 4 + g) ^ swz) * 8));
      }
      __builtin_amdgcn_s_setprio(1);
#pragma unroll
      for (int kk = 0; kk < 4; ++kk)
        sacc = __builtin_amdgcn_mfma_f32_16x16x32_bf16(kf[kk], qf[kk], sacc, 0, 0, 0);
      __builtin_amdgcn_s_setprio(0);
    }

    // ---- softmax (own subtile h): mask+scale, strip reduce ----
    {
      const int qg = q0 + h * 16 + i16;
      const int kvbase = kv0 + s8 * 16 + g * 4;
#pragma unroll
      for (int j = 0; j < 4; ++j) {
        const bool valid = (kvbase + j) <= qg;
        sacc[j] = valid ? sacc[j] * 0.03125f : -1e30f;
      }
      float pm = fmaxf(fmaxf(sacc[0], sacc[1]), fmaxf(sacc[2], sacc[3]));
      pm = fmaxf(pm, __shfl_xor(pm, 16));
      pm = fmaxf(pm, __shfl_xor(pm, 32));
      if (lane < 16) pmaxT[h * 16 + lane][s8] = pm;
    }
    __syncthreads();   // A: pmax partials visible

    // combine max for BOTH subtiles (every wave tracks both for PV rescale)
    float alpha[2];
#pragma unroll
    for (int nt = 0; nt < 2; ++nt) {
      const float* pr = &pmaxT[nt * 16 + i16][0];
      f32x4 a = *(const f32x4*)(pr);
      f32x4 b = *(const f32x4*)(pr + 4);
      float mx = fmaxf(fmaxf(fmaxf(a[0], a[1]), fmaxf(a[2], a[3])),
                       fmaxf(fmaxf(b[0], b[1]), fmaxf(b[2], b[3])));
      const float m_new = fmaxf(m_reg[nt], mx);
      alpha[nt] = __expf(m_reg[nt] - m_new);
      m_reg[nt] = m_new;
    }
    // P for own subtile h, with updated m_reg[h]
    {
      float ps = 0.f;
      u16x4 pw;
#pragma unroll
      for (int j = 0; j < 4; ++j) {
        const float p = __expf(sacc[j] - m_reg[h]);   // masked -> 0
        ps += p;
        pw[j] = f2bf(p);
      }
      const int pslot = (s8 * 2 + (g >> 1)) ^ swz;
      *(u16x4*)(Pl + (h * 16 + i16) * 128 + pslot * 8 + (g & 1) * 4) = pw;
      ps += __shfl_xor(ps, 16);
      ps += __shfl_xor(ps, 32);
      if (lane < 16) psumT[h * 16 + lane][s8] = ps;
    }
    __syncthreads();   // B: P + psum visible

    // ---- l update + O rescale ----
#pragma unroll
    for (int nt = 0; nt < 2; ++nt) {
      const float* pr = &psumT[nt * 16 + i16][0];
      f32x4 a = *(const f32x4*)(pr);
      f32x4 b = *(const f32x4*)(pr + 4);
      const float st = (a[0] + a[1] + a[2] + a[3]) + (b[0] + b[1] + b[2] + b[3]);
      l_reg[nt] = alpha[nt] * l_reg[nt] + st;
#pragma unroll
      for (int mt = 0; mt < 4; ++mt)
#pragma unroll
        for (int j = 0; j < 4; ++j) o_acc[mt][nt][j] *= alpha[nt];
    }

    // ---- PV: kc 0..3 with 2-deep V ring (A,B alternate) ----
#define PV_STEP(KC, VREG)                                                      \
    do {                                                                        \
      bf16x8 pfa = __builtin_bit_cast(bf16x8, *(const u16x8*)(                  \
          Pl + (0 * 16 + i16) * 128 + (((KC) * 4 + g) ^ swz) * 8));             \
      bf16x8 pfb = __builtin_bit_cast(bf16x8, *(const u16x8*)(                  \
          Pl + (1 * 16 + i16) * 128 + (((KC) * 4 + g) ^ swz) * 8));             \
      __builtin_amdgcn_s_setprio(1);                                            \
      _Pragma("unroll")                                                         \
      for (int mt = 0; mt < 4; ++mt) {                                          \
        o_acc[mt][0] = __builtin_amdgcn_mfma_f32_16x16x32_bf16(VREG[mt], pfa,   \
                                                               o_acc[mt][0], 0, 0, 0); \
        o_acc[mt][1] = __builtin_amdgcn_mfma_f32_16x16x32_bf16(VREG[mt], pfb,   \
                                                               o_acc[mt][1], 0, 0, 0); \
      }                                                                         \
      __builtin_amdgcn_s_setprio(0);                                            \
    } while (0)

    PV_STEP(0, vA);
#pragma unroll
    for (int mt = 0; mt < 4; ++mt)   // reload vA <- kc2 (hidden under PV1)
      vA[mt] = __builtin_bit_cast(bf16x8,
          *(const u16x8*)(vb + vt0 + 2 * PAN + (size_t)mt * 512));
    PV_STEP(1, vB);
#pragma unroll
    for (int mt = 0; mt < 4; ++mt)   // reload vB <- kc3 (hidden under PV2)
      vB[mt] = __builtin_bit_cast(bf16x8,
          *(const u16x8*)(vb + vt0 + 3 * PAN + (size_t)mt * 512));
    PV_STEP(2, vA);
    PV_STEP(3, vB);
#undef PV_STEP
    // (no barrier C: next tile's Pl/pmaxT writes are ordered by its own A/B)
  }

  // ---- epilogue: D slice wv*64 ----
  if (slot < 0) {
#pragma unroll
    for (int nt = 0; nt < 2; ++nt) {
      const float linv = 1.f / l_reg[nt];
      const size_t qoff = boff + (size_t)(q0 + nt * 16 + i16) * DIM + wv * 64 + g * 4;
#pragma unroll
      for (int mt = 0; mt < 4; ++mt) {
        f32x4 o;
#pragma unroll
        for (int j = 0; j < 4; ++j) o[j] = o_acc[mt][nt][j] * linv;
        *(f32x4*)(Out + qoff + mt * 16) = o;
      }
    }
  } else {
    const size_t pbase = (size_t)slot * (QBLK * DIM);
#pragma unroll
    for (int nt = 0; nt < 2; ++nt) {
      const size_t qoff = pbase + (size_t)(nt * 16 + i16) * DIM + wv * 64 + g * 4;
#pragma unroll
      for (int mt = 0; mt < 4; ++mt)
        *(f32x4*)(Opart + qoff + mt * 16) = o_acc[mt][nt];
    }
    if (wv == 0 && lane < 16) {
#pragma unroll
      for (int nt = 0; nt < 2; ++nt) {
        Ml[(size_t)slot * 64 + (nt * 16 + lane) * 2 + 0] = m_reg[nt];
        Ml[(size_t)slot * 64 + (nt * 16 + lane) * 2 + 1] = l_reg[nt];
      }
    }
  }
}

// Deterministic flash-merge of <=4 partials per (batch, qtile). 1024 threads.
__global__ __launch_bounds__(1024) void combine_kernel(
    const float* __restrict__ Opart, const float* __restrict__ Ml,
    float* __restrict__ Out, int mode) {
  const int NT  = (mode == 2) ? 48 : 32;
  const int qt0 = (mode == 2) ? 16 : 32;
  const int b   = blockIdx.x / NT;
  const int qt  = qt0 + blockIdx.x % NT;
  const int n   = (mode == 2) ? ((qt >> 4) + 1) : 2;

  int slots[4];
  if (mode == 2) {
    slots[0] = b * 144 + (qt - 16);
    slots[1] = b * 144 + 48 + (qt - 16);
    slots[2] = b * 144 + 96 + (qt - 32);
    slots[3] = b * 144 + 128 + (qt - 48);
  } else {
    slots[0] = b * 64 + (qt - 32);
    slots[1] = b * 64 + 32 + (qt - 32);
    slots[2] = slots[3] = 0;
  }

  __shared__ float wsh[4][32];
  __shared__ float lsh[32];
  const int t = threadIdx.x;   // 1024
  if (t < 32) {
    float mc[4], lc[4];
    float m = -1e30f;
#pragma unroll 4
    for (int c = 0; c < 4; ++c) {
      if (c < n) {
        mc[c] = Ml[(size_t)slots[c] * 64 + t * 2 + 0];
        lc[c] = Ml[(size_t)slots[c] * 64 + t * 2 + 1];
        m = fmaxf(m, mc[c]);
      }
    }
    float l = 0.f;
#pragma unroll 4
    for (int c = 0; c < 4; ++c) {
      if (c < n) {
        const float w = __expf(mc[c] - m);
        wsh[c][t] = w;
        l += w * lc[c];
      }
    }
    lsh[t] = 1.f / l;
  }
  __syncthreads();

  const size_t obase = ((size_t)b * SEQ + (size_t)qt * 32) * DIM;
#pragma unroll
  for (int k = 0; k < 8; ++k) {
    const int idx = k * 1024 + t;
    const int q   = idx >> 8;
    const int sl  = idx & 255;
    f32x4 acc = {0.f, 0.f, 0.f, 0.f};
#pragma unroll 4
    for (int c = 0; c < 4; ++c) {
      if (c < n) {
        f32x4 x = *(const f32x4*)(Opart + (size_t)slots[c] * (QBLK * DIM)
                                  + (size_t)q * DIM + sl * 4);
        const float w = wsh[c][q];
#pragma unroll
        for (int j = 0; j < 4; ++j) acc[j] += w * x[j];
      }
    }
    const float li = lsh[q];
    f32x4 o;
#pragma unroll
    for (int j = 0; j < 4; ++j) o[j] = acc[j] * li;
    *(f32x4*)(Out + obase + (size_t)q * DIM + sl * 4) = o;
  }
}

// Emergency fallback - correct, not fast.
__global__ void attn_naive(const float* __restrict__ Q, const float* __restrict__ K,
                           const float* __restrict__ V, float* __restrict__ Out) {
  const int b = blockIdx.y, q = blockIdx.x;
  const int t = threadIdx.x;
  __shared__ float qs[DIM];
  __shared__ float sc[SEQ];
  __shared__ float red[2];
  const size_t boff = (size_t)b * SEQ * DIM;
  for (int d = t; d < DIM; d += 256) qs[d] = Q[boff + (size_t)q * DIM + d];
  __syncthreads();
  const int kvmax = q + 1;
  for (int kv = t; kv < kvmax; kv += 256) {
    const float* kr = K + boff + (size_t)kv * DIM;
    float s = 0.f;
    for (int d = 0; d < DIM; ++d) s += qs[d] * kr[d];
    sc[kv] = s * 0.03125f;
  }
  __syncthreads();
  if (t == 0) {
    float m = -1e30f;
    for (int kv = 0; kv < kvmax; ++kv) m = fmaxf(m, sc[kv]);
    red[0] = m;
  }
  __syncthreads();
  const float m = red[0];
  for (int kv = t; kv < kvmax; kv += 256) sc[kv] = __expf(sc[kv] - m);
  __syncthreads();
  if (t == 0) {
    float l = 0.f;
    for (int kv = 0; kv < kvmax; ++kv) l += sc[kv];
    red[1] = l;
  }
  __syncthreads();
  const float linv = 1.f / red[1];
  for (int d = t; d < DIM; d += 256) {
    float o = 0.f;
    for (int kv = 0; kv < kvmax; ++kv) o += sc[kv] * V[boff + (size_t)kv * DIM + d];
    Out[boff + (size_t)q * DIM + d] = o * linv;
  }
}

extern "C" void kernel_launch(void* const* d_in, const int* in_sizes, int n_in,
                              void* d_out, int out_size, void* d_ws, size_t ws_size,
                              hipStream_t stream) {
  (void)in_sizes; (void)n_in; (void)out_size;
  const float* Q = (const float*)d_in[0];
  const float* K = (const float*)d_in[1];
  const float* V = (const float*)d_in[2];
  float* Out = (float*)d_out;

  const size_t nelem   = (size_t)B_SZ * SEQ * DIM;            // 8.4M / tensor
  const size_t bf_b    = nelem * sizeof(unsigned short);      // 16 MB
  const size_t ml_b    = (size_t)640 * 64 * sizeof(float);    // 160 KB (max)
  const size_t part1_b = (size_t)256 * QBLK * DIM * sizeof(float);   // 32 MB
  const size_t part2_b = (size_t)576 * QBLK * DIM * sizeof(float);   // 72 MB

  const size_t need0 = 2 * bf_b;
  const size_t need1 = 2 * bf_b + ml_b + part1_b;
  const size_t need2 = 2 * bf_b + ml_b + part2_b;

  const int mode = (ws_size >= need2) ? 2 : (ws_size >= need1) ? 1
                   : (ws_size >= need0) ? 0 : -1;

  if (mode < 0) {
    hipLaunchKernelGGL(attn_naive, dim3(SEQ, B_SZ), dim3(256), 0, stream, Q, K, V, Out);
    return;
  }

  unsigned short* Kp = (unsigned short*)d_ws;
  unsigned short* Vp = Kp + nelem;
  float* Ml    = (float*)(Vp + nelem);
  float* Opart = Ml + 640 * 64;

  hipLaunchKernelGGL(transpose_k_kernel, dim3(DIM / 128, SEQ / 16, B_SZ), dim3(256),
                     0, stream, K, Kp);
  hipLaunchKernelGGL(transpose_v_kernel, dim3(DIM / 32, SEQ / 32, B_SZ), dim3(256),
                     0, stream, V, Vp);

  const int grid = (mode == 2) ? 640 : (mode == 1) ? 384 : 256;
  hipLaunchKernelGGL(attn_part, dim3(grid), dim3(NWAVES * 64), 0, stream,
                     Q, Kp, Vp, Out, Opart, Ml, mode);

  if (mode >= 1) {
    const int cgrid = (mode == 2) ? (B_SZ * 48) : (B_SZ * 32);
    hipLaunchKernelGGL(combine_kernel, dim3(cgrid), dim3(1024), 0, stream,
                       Opart, Ml, Out, mode);
  }
}

// Round 15
// 205.983 us; speedup vs baseline: 1.0728x; 1.0728x over previous
//
#include <hip/hip_runtime.h>
#include <stdint.h>

// Causal attention, B=4, SQ=SK=2048, D=1024, fp32 in/out, bf16 MFMA compute.
// R15: QBLK=64 (K-frag registers reused across 4 q-subtiles -> L2->CU bytes
//      per unit work HALVED), 8 waves x 512 thr at the proven spill-free
//      (512,2) shape. kv-chunks of 256 (560 uniform blocks), partials bf16.
//      Same swapped-QK^T / register softmax / panel layouts / A,B barriers.
// Layouts: Kp[b][kv/16][d/8][kv%16][8d]; Vp[b][sk/32][d][sk%32].

#define B_SZ 4
#define SEQ 2048
#define DIM 1024
#define QBLK 64
#define KVBLK 128
#define NWAVES 8
#define PAN  ((size_t)DIM * 32)
#define KPAN ((size_t)DIM * 16)
#define NCHUNK 132          // chunk blocks per batch (qt 8..31, 256-kv chunks)
#define SLOTSZ 65536        // u16 elems per partial slot (64 x 1024)

typedef __bf16 bf16x8 __attribute__((ext_vector_type(8)));
typedef unsigned short u16x8 __attribute__((ext_vector_type(8)));
typedef unsigned short u16x4 __attribute__((ext_vector_type(4)));
typedef float f32x4 __attribute__((ext_vector_type(4)));

__device__ __forceinline__ unsigned short f2bf(float f) {
  union { float f; uint32_t u; } c; c.f = f;
  uint32_t u = c.u;
  u += 0x7FFFu + ((u >> 16) & 1u);   // RNE
  return (unsigned short)(u >> 16);
}

// K[b][kv][d] fp32 -> Kp[b][kv/16][d/8][kv%16][8] bf16
__global__ void transpose_k_kernel(const float* __restrict__ in,
                                   unsigned short* __restrict__ out) {
  const int b   = blockIdx.z;
  const int kv0 = blockIdx.y * 16;
  const int d0  = blockIdx.x * 128;
  const int t   = threadIdx.x;          // 256
  const int kvl = t >> 4;
  const int uu  = t & 15;
  const int d   = d0 + uu * 8;
  const float* src = in + (size_t)b * SEQ * DIM + (size_t)(kv0 + kvl) * DIM + d;
  f32x4 a = *(const f32x4*)(src);
  f32x4 c = *(const f32x4*)(src + 4);
  u16x8 pk;
#pragma unroll
  for (int j = 0; j < 4; ++j) { pk[j] = f2bf(a[j]); pk[4 + j] = f2bf(c[j]); }
  *(u16x8*)(out + (size_t)b * SEQ * DIM + (size_t)blockIdx.y * KPAN
            + (size_t)(d >> 3) * 128 + kvl * 8) = pk;
}

// V[b][sk][d] fp32 -> Vp[b][sk/32][d][sk%32] bf16
__global__ void transpose_v_kernel(const float* __restrict__ in,
                                   unsigned short* __restrict__ out) {
  __shared__ unsigned short tile[32][33];
  const int b  = blockIdx.z;
  const int s0 = blockIdx.y * 32;
  const int d0 = blockIdx.x * 32;
  const int t  = threadIdx.x;
  const int r  = t >> 3;
  const int c4 = (t & 7) * 4;
  const size_t ibase = (size_t)b * SEQ * DIM;
  const size_t obase = (size_t)b * DIM * SEQ;

  f32x4 v = *(const f32x4*)(in + ibase + (size_t)(s0 + r) * DIM + d0 + c4);
#pragma unroll
  for (int j = 0; j < 4; ++j) tile[r][c4 + j] = f2bf(v[j]);
  __syncthreads();
  u16x4 o;
#pragma unroll
  for (int j = 0; j < 4; ++j) o[j] = tile[c4 + j][r];
  *(u16x4*)(out + obase + (size_t)(s0 >> 5) * PAN + (size_t)(d0 + r) * 32 + c4) = o;
}

__device__ __forceinline__ int imin(int a, int b) { return a < b ? a : b; }

__global__ __launch_bounds__(512, 2) void attn_part(
    const float* __restrict__ Qf, const unsigned short* __restrict__ Kp,
    const unsigned short* __restrict__ Vp, float* __restrict__ Out,
    unsigned short* __restrict__ Opart, float* __restrict__ Ml) {
  const int tid  = threadIdx.x;
  const int lane = tid & 63;
  const int wv   = tid >> 6;        // 0..7: kv strip (QK) and 128-wide D slice (PV)
  const int g    = lane >> 4;
  const int i16  = lane & 15;
  const int swz  = i16 & 7;

  // ---- decode: bid -> (batch, qt, chunk); heavy-first (qt descending) ----
  const int bid   = blockIdx.x;          // 0..559
  const int batch = bid & 3;
  const int r     = bid >> 2;            // 0..139
  int qt, kvlo, kvhi, slot;
  if (r < NCHUNK) {
    int rr = r, q = 31;
    for (; q >= 8; --q) { const int nc = (q + 4) >> 2; if (rr < nc) break; rr -= nc; }
    qt = q; kvlo = rr * 256; kvhi = imin(kvlo + 256, 64 * qt + 64);
    slot = batch * NCHUNK + r;
  } else {
    qt = r - NCHUNK; kvlo = 0; kvhi = 64 * qt + 64; slot = -1;   // qt 0..7 direct
  }

  const int q0 = qt * QBLK;
  const size_t boff = (size_t)batch * SEQ * DIM;

  __shared__ __align__(16) unsigned short Qs[QBLK * 1024];   // 128 KB swizzled
  __shared__ __align__(16) unsigned short Pl[QBLK * KVBLK];  // 16 KB swizzled
  __shared__ float pmaxT[QBLK][12];
  __shared__ float psumT[QBLK][12];

  // ---- stage Q: fp32 -> bf16 LDS, 16B-slot XOR swizzle (slot ^ (row&7)) ----
  {
    const int row = tid >> 3;          // 0..63
    const int s0  = tid & 7;
    const float* qrow = Qf + boff + (size_t)(q0 + row) * DIM;
#pragma unroll
    for (int k = 0; k < 16; ++k) {
      const int slot2 = s0 + 8 * k;    // 128 slots of 8 bf16
      f32x4 a = *(const f32x4*)(qrow + slot2 * 8);
      f32x4 b = *(const f32x4*)(qrow + slot2 * 8 + 4);
      u16x8 pk;
#pragma unroll
      for (int j = 0; j < 4; ++j) { pk[j] = f2bf(a[j]); pk[4 + j] = f2bf(b[j]); }
      *(u16x8*)(Qs + row * 1024 + (slot2 ^ (row & 7)) * 8) = pk;
    }
  }

  const f32x4 zero4 = {0.f, 0.f, 0.f, 0.f};
  f32x4 o_acc[8][4];                  // [mt d-16][nt q-16] = 128 AGPR
#pragma unroll
  for (int mt = 0; mt < 8; ++mt)
#pragma unroll
    for (int nt = 0; nt < 4; ++nt) o_acc[mt][nt] = zero4;

  float m_reg[4] = {-1e30f, -1e30f, -1e30f, -1e30f};
  float l_reg[4] = {0.f, 0.f, 0.f, 0.f};

  const int ntiles = (kvhi - kvlo + KVBLK - 1) >> 7;
  const unsigned short* kb = Kp + boff + (size_t)wv * KPAN + i16 * 8;
  const unsigned short* vb = Vp + boff + (size_t)(wv * 128 + i16) * 32 + g * 8;

  __syncthreads();   // Q visible

  for (int t = 0; t < ntiles; ++t) {
    const int kv0 = kvlo + t * KVBLK;
    const unsigned short* kt = kb + (size_t)(kv0 >> 4) * KPAN;
    const size_t vt0 = (size_t)(kv0 >> 5) * PAN;

    f32x4 sacc[4];
#pragma unroll
    for (int nt = 0; nt < 4; ++nt) sacc[nt] = zero4;
    bf16x8 vV[8];

    // ---- QK^T: 8 phases; kf reused across 4 q-subtiles (the R15 lever) ----
#pragma unroll
    for (int c = 0; c < 8; ++c) {
      if (c == 0) {   // issue V frags for kc0 early (hidden under QK)
#pragma unroll
        for (int mt = 0; mt < 8; ++mt)
          vV[mt] = __builtin_bit_cast(bf16x8,
              *(const u16x8*)(vb + vt0 + (size_t)mt * 512));
      }
      bf16x8 kf[4];
#pragma unroll
      for (int kk = 0; kk < 4; ++kk)
        kf[kk] = __builtin_bit_cast(bf16x8,
            *(const u16x8*)(kt + (size_t)(c * 16 + kk * 4 + g) * 128));
#pragma unroll
      for (int nt = 0; nt < 4; ++nt) {
        const unsigned short* qrb = Qs + (nt * 16 + i16) * 1024;
        bf16x8 qf[4];
#pragma unroll
        for (int kk = 0; kk < 4; ++kk)
          qf[kk] = __builtin_bit_cast(bf16x8,
              *(const u16x8*)(qrb + ((c * 16 + kk * 4 + g) ^ swz) * 8));
        __builtin_amdgcn_s_setprio(1);
#pragma unroll
        for (int kk = 0; kk < 4; ++kk)
          sacc[nt] = __builtin_amdgcn_mfma_f32_16x16x32_bf16(kf[kk], qf[kk], sacc[nt], 0, 0, 0);
        __builtin_amdgcn_s_setprio(0);
      }
    }

    // ---- softmax: mask+scale, strip reduce over g ----
    float pm[4];
#pragma unroll
    for (int nt = 0; nt < 4; ++nt) {
      const int qg = q0 + nt * 16 + i16;
      const int kvbase = kv0 + wv * 16 + g * 4;
#pragma unroll
      for (int j = 0; j < 4; ++j) {
        const bool valid = (kvbase + j) <= qg;
        sacc[nt][j] = valid ? sacc[nt][j] * 0.03125f : -1e30f;
      }
      float v = fmaxf(fmaxf(sacc[nt][0], sacc[nt][1]), fmaxf(sacc[nt][2], sacc[nt][3]));
      v = fmaxf(v, __shfl_xor(v, 16));
      v = fmaxf(v, __shfl_xor(v, 32));
      pm[nt] = v;
    }
    if (lane < 16) {
#pragma unroll
      for (int nt = 0; nt < 4; ++nt) pmaxT[nt * 16 + lane][wv] = pm[nt];
    }
    __syncthreads();   // A: pmax partials visible

    float alpha[4];
#pragma unroll
    for (int nt = 0; nt < 4; ++nt) {
      const float* pr = &pmaxT[nt * 16 + i16][0];
      f32x4 a = *(const f32x4*)(pr);
      f32x4 b = *(const f32x4*)(pr + 4);
      float mx = fmaxf(fmaxf(fmaxf(a[0], a[1]), fmaxf(a[2], a[3])),
                       fmaxf(fmaxf(b[0], b[1]), fmaxf(b[2], b[3])));
      const float m_new = fmaxf(m_reg[nt], mx);
      alpha[nt] = __expf(m_reg[nt] - m_new);
      m_reg[nt] = m_new;

      float ps = 0.f;
      u16x4 pw;
#pragma unroll
      for (int j = 0; j < 4; ++j) {
        const float p = __expf(sacc[nt][j] - m_new);   // masked -> 0
        ps += p;
        pw[j] = f2bf(p);
      }
      const int pslot = (wv * 2 + (g >> 1)) ^ swz;
      *(u16x4*)(Pl + (nt * 16 + i16) * 128 + pslot * 8 + (g & 1) * 4) = pw;
      ps += __shfl_xor(ps, 16);
      ps += __shfl_xor(ps, 32);
      pm[nt] = ps;
    }
    if (lane < 16) {
#pragma unroll
      for (int nt = 0; nt < 4; ++nt) psumT[nt * 16 + lane][wv] = pm[nt];
    }
    __syncthreads();   // B: P + psum visible

    // ---- l update + O rescale ----
#pragma unroll
    for (int nt = 0; nt < 4; ++nt) {
      const float* pr = &psumT[nt * 16 + i16][0];
      f32x4 a = *(const f32x4*)(pr);
      f32x4 b = *(const f32x4*)(pr + 4);
      const float st = (a[0] + a[1] + a[2] + a[3]) + (b[0] + b[1] + b[2] + b[3]);
      l_reg[nt] = alpha[nt] * l_reg[nt] + st;
#pragma unroll
      for (int mt = 0; mt < 8; ++mt)
#pragma unroll
        for (int j = 0; j < 4; ++j) o_acc[mt][nt][j] *= alpha[nt];
    }

    // ---- PV: kc 0..3; 32 MFMA per 8 V loads ----
#pragma unroll
    for (int kc = 0; kc < 4; ++kc) {
      if (kc > 0) {
#pragma unroll
        for (int mt = 0; mt < 8; ++mt)
          vV[mt] = __builtin_bit_cast(bf16x8,
              *(const u16x8*)(vb + vt0 + (size_t)kc * PAN + (size_t)mt * 512));
      }
#pragma unroll
      for (int nt = 0; nt < 4; ++nt) {
        bf16x8 pf = __builtin_bit_cast(bf16x8, *(const u16x8*)(
            Pl + (nt * 16 + i16) * 128 + (((kc * 4 + g) ^ swz) * 8)));
        __builtin_amdgcn_s_setprio(1);
#pragma unroll
        for (int mt = 0; mt < 8; ++mt)
          o_acc[mt][nt] = __builtin_amdgcn_mfma_f32_16x16x32_bf16(vV[mt], pf,
                                                                  o_acc[mt][nt], 0, 0, 0);
        __builtin_amdgcn_s_setprio(0);
      }
    }
    // (no barrier C: next tile's Pl/pmaxT writes ordered by its own A/B)
  }

  // ---- epilogue ----
  if (slot < 0) {
#pragma unroll
    for (int nt = 0; nt < 4; ++nt) {
      const float linv = 1.f / l_reg[nt];
      const size_t qoff = boff + (size_t)(q0 + nt * 16 + i16) * DIM + wv * 128 + g * 4;
#pragma unroll
      for (int mt = 0; mt < 8; ++mt) {
        f32x4 o;
#pragma unroll
        for (int j = 0; j < 4; ++j) o[j] = o_acc[mt][nt][j] * linv;
        *(f32x4*)(Out + qoff + mt * 16) = o;
      }
    }
  } else {
    unsigned short* op = Opart + (size_t)slot * SLOTSZ;
#pragma unroll
    for (int nt = 0; nt < 4; ++nt) {
#pragma unroll
      for (int mt = 0; mt < 8; ++mt) {
        u16x4 pw;
#pragma unroll
        for (int j = 0; j < 4; ++j) pw[j] = f2bf(o_acc[mt][nt][j]);
        *(u16x4*)(op + (size_t)(nt * 16 + i16) * 1024 + wv * 128 + mt * 16 + g * 4) = pw;
      }
    }
    if (wv == 0 && lane < 16) {
#pragma unroll
      for (int nt = 0; nt < 4; ++nt) {
        Ml[(size_t)slot * 128 + (nt * 16 + lane) * 2 + 0] = m_reg[nt];
        Ml[(size_t)slot * 128 + (nt * 16 + lane) * 2 + 1] = l_reg[nt];
      }
    }
  }
}

// Deterministic flash-merge of <=8 bf16 partials per (batch, qt64).
__global__ __launch_bounds__(1024) void combine_kernel(
    const unsigned short* __restrict__ Opart, const float* __restrict__ Ml,
    float* __restrict__ Out) {
  const int b  = blockIdx.x & 3;
  const int qt = 8 + (blockIdx.x >> 2);   // 8..31
  int rbase = 0;
  for (int q = 31; q > qt; --q) rbase += (q + 4) >> 2;
  const int n = (qt + 4) >> 2;            // 3..8 chunks
  const int sbase = b * NCHUNK + rbase;   // chunks c ascending

  __shared__ float wsh[8][64];
  __shared__ float lsh[64];
  const int t = threadIdx.x;   // 1024
  if (t < 64) {
    float mc[8], lc[8];
    float m = -1e30f;
    for (int c = 0; c < n; ++c) {
      mc[c] = Ml[(size_t)(sbase + c) * 128 + t * 2 + 0];
      lc[c] = Ml[(size_t)(sbase + c) * 128 + t * 2 + 1];
      m = fmaxf(m, mc[c]);
    }
    float l = 0.f;
    for (int c = 0; c < n; ++c) {
      const float w = __expf(mc[c] - m);
      wsh[c][t] = w;
      l += w * lc[c];
    }
    lsh[t] = 1.f / l;
  }
  __syncthreads();

  const size_t obase = ((size_t)b * SEQ + (size_t)qt * 64) * DIM;
#pragma unroll
  for (int k = 0; k < 16; ++k) {
    const int idx = k * 1024 + t;
    const int q   = idx >> 8;          // 0..63
    const int sl  = idx & 255;
    f32x4 acc = {0.f, 0.f, 0.f, 0.f};
    for (int c = 0; c < n; ++c) {
      u16x4 x = *(const u16x4*)(Opart + (size_t)(sbase + c) * SLOTSZ
                                + (size_t)q * 1024 + sl * 4);
      const float w = wsh[c][q];
#pragma unroll
      for (int j = 0; j < 4; ++j) {
        union { float f; uint32_t u; } cv; cv.u = ((uint32_t)x[j]) << 16;
        acc[j] += w * cv.f;
      }
    }
    const float li = lsh[q];
    f32x4 o;
#pragma unroll
    for (int j = 0; j < 4; ++j) o[j] = acc[j] * li;
    *(f32x4*)(Out + obase + (size_t)q * DIM + sl * 4) = o;
  }
}

// Emergency fallback - correct, not fast.
__global__ void attn_naive(const float* __restrict__ Q, const float* __restrict__ K,
                           const float* __restrict__ V, float* __restrict__ Out) {
  const int b = blockIdx.y, q = blockIdx.x;
  const int t = threadIdx.x;
  __shared__ float qs[DIM];
  __shared__ float sc[SEQ];
  __shared__ float red[2];
  const size_t boff = (size_t)b * SEQ * DIM;
  for (int d = t; d < DIM; d += 256) qs[d] = Q[boff + (size_t)q * DIM + d];
  __syncthreads();
  const int kvmax = q + 1;
  for (int kv = t; kv < kvmax; kv += 256) {
    const float* kr = K + boff + (size_t)kv * DIM;
    float s = 0.f;
    for (int d = 0; d < DIM; ++d) s += qs[d] * kr[d];
    sc[kv] = s * 0.03125f;
  }
  __syncthreads();
  if (t == 0) {
    float m = -1e30f;
    for (int kv = 0; kv < kvmax; ++kv) m = fmaxf(m, sc[kv]);
    red[0] = m;
  }
  __syncthreads();
  const float m = red[0];
  for (int kv = t; kv < kvmax; kv += 256) sc[kv] = __expf(sc[kv] - m);
  __syncthreads();
  if (t == 0) {
    float l = 0.f;
    for (int kv = 0; kv < kvmax; ++kv) l += sc[kv];
    red[1] = l;
  }
  __syncthreads();
  const float linv = 1.f / red[1];
  for (int d = t; d < DIM; d += 256) {
    float o = 0.f;
    for (int kv = 0; kv < kvmax; ++kv) o += sc[kv] * V[boff + (size_t)kv * DIM + d];
    Out[boff + (size_t)q * DIM + d] = o * linv;
  }
}

extern "C" void kernel_launch(void* const* d_in, const int* in_sizes, int n_in,
                              void* d_out, int out_size, void* d_ws, size_t ws_size,
                              hipStream_t stream) {
  (void)in_sizes; (void)n_in; (void)out_size;
  const float* Q = (const float*)d_in[0];
  const float* K = (const float*)d_in[1];
  const float* V = (const float*)d_in[2];
  float* Out = (float*)d_out;

  const size_t nelem  = (size_t)B_SZ * SEQ * DIM;                    // 8.4M
  const size_t bf_b   = nelem * sizeof(unsigned short);              // 16.8 MB
  const size_t nslots = (size_t)B_SZ * NCHUNK;                       // 528
  const size_t ml_b   = nslots * 128 * sizeof(float);                // 270 KB
  const size_t op_b   = nslots * SLOTSZ * sizeof(unsigned short);    // 69.2 MB
  const size_t need   = 2 * bf_b + ml_b + op_b;                      // ~103 MB

  if (ws_size < need) {
    hipLaunchKernelGGL(attn_naive, dim3(SEQ, B_SZ), dim3(256), 0, stream, Q, K, V, Out);
    return;
  }

  unsigned short* Kp = (unsigned short*)d_ws;
  unsigned short* Vp = Kp + nelem;
  float* Ml = (float*)(Vp + nelem);
  unsigned short* Opart = (unsigned short*)(Ml + nslots * 128);

  hipLaunchKernelGGL(transpose_k_kernel, dim3(DIM / 128, SEQ / 16, B_SZ), dim3(256),
                     0, stream, K, Kp);
  hipLaunchKernelGGL(transpose_v_kernel, dim3(DIM / 32, SEQ / 32, B_SZ), dim3(256),
                     0, stream, V, Vp);

  hipLaunchKernelGGL(attn_part, dim3(B_SZ * (NCHUNK + 8)), dim3(NWAVES * 64),
                     0, stream, Q, Kp, Vp, Out, Opart, Ml);

  hipLaunchKernelGGL(combine_kernel, dim3(B_SZ * 24), dim3(1024), 0, stream,
                     Opart, Ml, Out);
}